// Round 1
// baseline (1708.639 us; speedup 1.0000x reference)
//
#include <hip/hip_runtime.h>
#include <hip/hip_bf16.h>

#define D_MODEL 1024
#define NHEAD 16
#define HEAD_DIM 64
#define BATCH 2
#define SEQ 2048
#define NROWS (BATCH * SEQ)   // 4096

// ---------------- GEMM: y = A @ W + bias ----------------
// A: [M x 1024] row-major, W: [1024 x 1024] row-major (in,out), bias [1024]
// SCATTER=true: write to [B,H,S,Dh] layout; else row-major [M,1024].
#define BM 128
#define BN 128
#define BK 16
#define LDP 132  // padded leading dim for LDS tiles

template <bool SCATTER>
__global__ __launch_bounds__(256) void gemm_kernel(const float* __restrict__ A,
                                                   const float* __restrict__ W,
                                                   const float* __restrict__ bias,
                                                   float* __restrict__ out) {
    __shared__ float As[BK][LDP];
    __shared__ float Bs[BK][LDP];

    const int tid = threadIdx.x;
    const int tx = tid & 15;          // 0..15 -> output cols
    const int ty = tid >> 4;          // 0..15 -> output rows
    const int bm = blockIdx.y;
    const int bn = blockIdx.x;

    // global load indices
    const int arow = tid >> 2;            // 0..63
    const int acol = (tid & 3) << 2;      // 0,4,8,12
    const int brow = tid >> 5;            // 0..7
    const int bcol = (tid & 31) << 2;     // 0..124

    const float* Ag = A + (size_t)(bm * BM + arow) * D_MODEL + acol;
    const float* Bg = W + (size_t)brow * D_MODEL + bn * BN + bcol;

    float acc[8][8];
#pragma unroll
    for (int i = 0; i < 8; ++i)
#pragma unroll
        for (int j = 0; j < 8; ++j) acc[i][j] = 0.f;

    for (int k0 = 0; k0 < D_MODEL; k0 += BK) {
        float4 a0 = *(const float4*)(Ag);
        float4 a1 = *(const float4*)(Ag + 64 * D_MODEL);
        float4 b0 = *(const float4*)(Bg);
        float4 b1 = *(const float4*)(Bg + 8 * D_MODEL);
        __syncthreads();  // previous iter's LDS reads done before overwrite
        As[acol + 0][arow] = a0.x;
        As[acol + 1][arow] = a0.y;
        As[acol + 2][arow] = a0.z;
        As[acol + 3][arow] = a0.w;
        As[acol + 0][arow + 64] = a1.x;
        As[acol + 1][arow + 64] = a1.y;
        As[acol + 2][arow + 64] = a1.z;
        As[acol + 3][arow + 64] = a1.w;
        *(float4*)&Bs[brow][bcol] = b0;
        *(float4*)&Bs[brow + 8][bcol] = b1;
        __syncthreads();
#pragma unroll
        for (int kk = 0; kk < BK; ++kk) {
            float4 fa0 = *(const float4*)&As[kk][ty * 4];
            float4 fa1 = *(const float4*)&As[kk][ty * 4 + 64];
            float4 fb0 = *(const float4*)&Bs[kk][tx * 4];
            float4 fb1 = *(const float4*)&Bs[kk][tx * 4 + 64];
            float av[8] = {fa0.x, fa0.y, fa0.z, fa0.w, fa1.x, fa1.y, fa1.z, fa1.w};
            float bv[8] = {fb0.x, fb0.y, fb0.z, fb0.w, fb1.x, fb1.y, fb1.z, fb1.w};
#pragma unroll
            for (int i = 0; i < 8; ++i)
#pragma unroll
                for (int j = 0; j < 8; ++j) acc[i][j] += av[i] * bv[j];
        }
        Ag += BK;
        Bg += (size_t)BK * D_MODEL;
    }

    // epilogue
    const int rbase[2] = {bm * BM + ty * 4, bm * BM + ty * 4 + 64};
    const int cbase[2] = {bn * BN + tx * 4, bn * BN + tx * 4 + 64};
    float4 bias4[2];
    bias4[0] = *(const float4*)(bias + cbase[0]);
    bias4[1] = *(const float4*)(bias + cbase[1]);

#pragma unroll
    for (int rh = 0; rh < 2; ++rh) {
#pragma unroll
        for (int ii = 0; ii < 4; ++ii) {
            const int m = rbase[rh] + ii;
            const int i = rh * 4 + ii;
#pragma unroll
            for (int ch = 0; ch < 2; ++ch) {
                const int c = cbase[ch];
                float4 val;
                val.x = acc[i][ch * 4 + 0] + bias4[ch].x;
                val.y = acc[i][ch * 4 + 1] + bias4[ch].y;
                val.z = acc[i][ch * 4 + 2] + bias4[ch].z;
                val.w = acc[i][ch * 4 + 3] + bias4[ch].w;
                if (SCATTER) {
                    const int b = m >> 11;          // m / 2048
                    const int s = m & 2047;
                    const int hh = c >> 6;          // head
                    const int d = c & 63;
                    float* dst = out + ((size_t)(b * NHEAD + hh) * SEQ + s) * HEAD_DIM + d;
                    *(float4*)dst = val;
                } else {
                    *(float4*)(out + (size_t)m * D_MODEL + c) = val;
                }
            }
        }
    }
}

// ---------------- Flash attention (fp32) ----------------
// q,k,v in [B,H,S,Dh]; output written to ao in [B,S,D] layout.
__global__ __launch_bounds__(256) void attn_kernel(const float* __restrict__ q,
                                                   const float* __restrict__ k,
                                                   const float* __restrict__ v,
                                                   float* __restrict__ ao) {
    __shared__ float Ks[64 * 64];
    __shared__ float Vs[64 * 64];

    const int tid = threadIdx.x;
    const int h = blockIdx.y;
    const int b = blockIdx.z;
    const int bh = b * NHEAD + h;
    const int srow = blockIdx.x * 256 + tid;

    const float scale = 0.125f;  // 1/sqrt(64)

    const float* qrow = q + ((size_t)bh * SEQ + srow) * HEAD_DIM;
    float qr[64];
#pragma unroll
    for (int j = 0; j < 16; ++j) {
        float4 t = *(const float4*)(qrow + 4 * j);
        qr[4 * j + 0] = t.x * scale;
        qr[4 * j + 1] = t.y * scale;
        qr[4 * j + 2] = t.z * scale;
        qr[4 * j + 3] = t.w * scale;
    }
    float o[64];
#pragma unroll
    for (int d = 0; d < 64; ++d) o[d] = 0.f;
    float mrun = -1e30f, lrun = 0.f;

    const float* kbase = k + (size_t)bh * SEQ * HEAD_DIM;
    const float* vbase = v + (size_t)bh * SEQ * HEAD_DIM;

    for (int kt = 0; kt < SEQ / 64; ++kt) {
        __syncthreads();
#pragma unroll
        for (int i = 0; i < 4; ++i) {
            const int idx = i * 1024 + tid * 4;
            *(float4*)&Ks[idx] = *(const float4*)(kbase + (size_t)kt * 4096 + idx);
            *(float4*)&Vs[idx] = *(const float4*)(vbase + (size_t)kt * 4096 + idx);
        }
        __syncthreads();

        for (int kk = 0; kk < 64; ++kk) {
            const float4* kr = (const float4*)&Ks[kk * 64];
            float s0 = 0.f, s1 = 0.f, s2 = 0.f, s3 = 0.f;
#pragma unroll
            for (int j = 0; j < 16; ++j) {
                float4 kv = kr[j];
                s0 += qr[4 * j + 0] * kv.x;
                s1 += qr[4 * j + 1] * kv.y;
                s2 += qr[4 * j + 2] * kv.z;
                s3 += qr[4 * j + 3] * kv.w;
            }
            const float s = (s0 + s1) + (s2 + s3);

            float p;
            if (s > mrun) {
                const float c = __expf(mrun - s);
                lrun *= c;
#pragma unroll
                for (int d = 0; d < 64; ++d) o[d] *= c;
                mrun = s;
                p = 1.f;
            } else {
                p = __expf(s - mrun);
            }
            lrun += p;

            const float4* vr = (const float4*)&Vs[kk * 64];
#pragma unroll
            for (int j = 0; j < 16; ++j) {
                float4 vv = vr[j];
                o[4 * j + 0] += p * vv.x;
                o[4 * j + 1] += p * vv.y;
                o[4 * j + 2] += p * vv.z;
                o[4 * j + 3] += p * vv.w;
            }
        }
    }

    const float inv = 1.f / lrun;
    float* dst = ao + ((size_t)b * SEQ + srow) * D_MODEL + h * HEAD_DIM;
#pragma unroll
    for (int j = 0; j < 16; ++j) {
        float4 t;
        t.x = o[4 * j + 0] * inv;
        t.y = o[4 * j + 1] * inv;
        t.z = o[4 * j + 2] * inv;
        t.w = o[4 * j + 3] * inv;
        *(float4*)&dst[4 * j] = t;
    }
}

extern "C" void kernel_launch(void* const* d_in, const int* in_sizes, int n_in,
                              void* d_out, int out_size, void* d_ws, size_t ws_size,
                              hipStream_t stream) {
    const float* x  = (const float*)d_in[0];
    const float* wq = (const float*)d_in[1];
    const float* bq = (const float*)d_in[2];
    const float* wk = (const float*)d_in[3];
    const float* bk = (const float*)d_in[4];
    const float* wv = (const float*)d_in[5];
    const float* bv = (const float*)d_in[6];
    const float* wo = (const float*)d_in[7];
    const float* bo = (const float*)d_in[8];
    float* out = (float*)d_out;

    const size_t PER = (size_t)BATCH * NHEAD * SEQ * HEAD_DIM;  // 4,194,304 floats
    float* qb = (float*)d_ws;
    float* kb = qb + PER;
    float* vb = kb + PER;
    float* ao = vb + PER;  // [NROWS, D_MODEL]

    dim3 gblock(256);
    dim3 ggrid(D_MODEL / BN, NROWS / BM);  // (8, 32)

    gemm_kernel<true><<<ggrid, gblock, 0, stream>>>(x, wq, bq, qb);
    gemm_kernel<true><<<ggrid, gblock, 0, stream>>>(x, wk, bk, kb);
    gemm_kernel<true><<<ggrid, gblock, 0, stream>>>(x, wv, bv, vb);

    dim3 ablock(256);
    dim3 agrid(SEQ / 256, NHEAD, BATCH);  // (8, 16, 2)
    attn_kernel<<<agrid, ablock, 0, stream>>>(qb, kb, vb, ao);

    gemm_kernel<false><<<ggrid, gblock, 0, stream>>>(ao, wo, bo, out);
}

// Round 2
// 684.741 us; speedup vs baseline: 2.4953x; 2.4953x over previous
//
#include <hip/hip_runtime.h>
#include <hip/hip_bf16.h>

#define D_MODEL 1024
#define NHEAD 16
#define HEAD_DIM 64
#define BATCH 2
#define SEQ 2048
#define NROWS (BATCH * SEQ)   // 4096

typedef __attribute__((ext_vector_type(8))) short bf16x8;
typedef __attribute__((ext_vector_type(4))) float f32x4;

__device__ __forceinline__ short f2bf(float f) {
    __hip_bfloat16 h = __float2bfloat16(f);
    return __builtin_bit_cast(short, h);
}

// ---------------- GEMM: y = A @ W + bias (fp32, unchanged) ----------------
#define BM 128
#define BN 128
#define BK 16
#define LDP 132

template <bool SCATTER>
__global__ __launch_bounds__(256) void gemm_kernel(const float* __restrict__ A,
                                                   const float* __restrict__ W,
                                                   const float* __restrict__ bias,
                                                   float* __restrict__ out) {
    __shared__ float As[BK][LDP];
    __shared__ float Bs[BK][LDP];

    const int tid = threadIdx.x;
    const int tx = tid & 15;
    const int ty = tid >> 4;
    const int bm = blockIdx.y;
    const int bn = blockIdx.x;

    const int arow = tid >> 2;
    const int acol = (tid & 3) << 2;
    const int brow = tid >> 5;
    const int bcol = (tid & 31) << 2;

    const float* Ag = A + (size_t)(bm * BM + arow) * D_MODEL + acol;
    const float* Bg = W + (size_t)brow * D_MODEL + bn * BN + bcol;

    float acc[8][8];
#pragma unroll
    for (int i = 0; i < 8; ++i)
#pragma unroll
        for (int j = 0; j < 8; ++j) acc[i][j] = 0.f;

    for (int k0 = 0; k0 < D_MODEL; k0 += BK) {
        float4 a0 = *(const float4*)(Ag);
        float4 a1 = *(const float4*)(Ag + 64 * D_MODEL);
        float4 b0 = *(const float4*)(Bg);
        float4 b1 = *(const float4*)(Bg + 8 * D_MODEL);
        __syncthreads();
        As[acol + 0][arow] = a0.x;
        As[acol + 1][arow] = a0.y;
        As[acol + 2][arow] = a0.z;
        As[acol + 3][arow] = a0.w;
        As[acol + 0][arow + 64] = a1.x;
        As[acol + 1][arow + 64] = a1.y;
        As[acol + 2][arow + 64] = a1.z;
        As[acol + 3][arow + 64] = a1.w;
        *(float4*)&Bs[brow][bcol] = b0;
        *(float4*)&Bs[brow + 8][bcol] = b1;
        __syncthreads();
#pragma unroll
        for (int kk = 0; kk < BK; ++kk) {
            float4 fa0 = *(const float4*)&As[kk][ty * 4];
            float4 fa1 = *(const float4*)&As[kk][ty * 4 + 64];
            float4 fb0 = *(const float4*)&Bs[kk][tx * 4];
            float4 fb1 = *(const float4*)&Bs[kk][tx * 4 + 64];
            float av[8] = {fa0.x, fa0.y, fa0.z, fa0.w, fa1.x, fa1.y, fa1.z, fa1.w};
            float bv[8] = {fb0.x, fb0.y, fb0.z, fb0.w, fb1.x, fb1.y, fb1.z, fb1.w};
#pragma unroll
            for (int i = 0; i < 8; ++i)
#pragma unroll
                for (int j = 0; j < 8; ++j) acc[i][j] += av[i] * bv[j];
        }
        Ag += BK;
        Bg += (size_t)BK * D_MODEL;
    }

    const int rbase[2] = {bm * BM + ty * 4, bm * BM + ty * 4 + 64};
    const int cbase[2] = {bn * BN + tx * 4, bn * BN + tx * 4 + 64};
    float4 bias4[2];
    bias4[0] = *(const float4*)(bias + cbase[0]);
    bias4[1] = *(const float4*)(bias + cbase[1]);

#pragma unroll
    for (int rh = 0; rh < 2; ++rh) {
#pragma unroll
        for (int ii = 0; ii < 4; ++ii) {
            const int m = rbase[rh] + ii;
            const int i = rh * 4 + ii;
#pragma unroll
            for (int ch = 0; ch < 2; ++ch) {
                const int c = cbase[ch];
                float4 val;
                val.x = acc[i][ch * 4 + 0] + bias4[ch].x;
                val.y = acc[i][ch * 4 + 1] + bias4[ch].y;
                val.z = acc[i][ch * 4 + 2] + bias4[ch].z;
                val.w = acc[i][ch * 4 + 3] + bias4[ch].w;
                if (SCATTER) {
                    const int b = m >> 11;
                    const int s = m & 2047;
                    const int hh = c >> 6;
                    const int d = c & 63;
                    float* dst = out + ((size_t)(b * NHEAD + hh) * SEQ + s) * HEAD_DIM + d;
                    *(float4*)dst = val;
                } else {
                    *(float4*)(out + (size_t)m * D_MODEL + c) = val;
                }
            }
        }
    }
}

// ---------------- Flash attention, bf16 MFMA ----------------
// q,k,v fp32 in [B,H,S,Dh]; output fp32 to ao in [B,S,D].
// Block: 256 thr = 4 waves; wave owns 32 q-rows; K/V tiles of 64.
#define KB 64
#define PITCH 72  // bf16 row pitch (144B) to spread LDS banks

__global__ __launch_bounds__(256) void attn_mfma_kernel(const float* __restrict__ q,
                                                        const float* __restrict__ k,
                                                        const float* __restrict__ v,
                                                        float* __restrict__ ao) {
    __shared__ short Ks[KB][PITCH];
    __shared__ short Vt[HEAD_DIM][PITCH];     // transposed: [d][k]
    __shared__ short Ps[4][32][PITCH];        // per-wave P tile [q][k]

    const int tid = threadIdx.x;
    const int wid = tid >> 6;
    const int lane = tid & 63;
    const int a = lane & 15;   // MFMA "A row / B col / D col" index
    const int g = lane >> 4;   // MFMA k-group

    const int bid = blockIdx.x;
    const int bh = bid >> 4;       // 32 (b,h) pairs; 16 q-chunks each
    const int qc = bid & 15;
    const int q0w = qc * 128 + wid * 32;

    const size_t base = (size_t)bh * SEQ * HEAD_DIM;

    // ---- Q fragments, scaled by 1/sqrt(64), held in registers ----
    bf16x8 qf[2][2];  // [qh][kc]
#pragma unroll
    for (int qh = 0; qh < 2; ++qh)
#pragma unroll
        for (int kc = 0; kc < 2; ++kc) {
            const float* src = q + base + (size_t)(q0w + qh * 16 + a) * HEAD_DIM + kc * 32 + g * 8;
            float4 f0 = *(const float4*)src;
            float4 f1 = *(const float4*)(src + 4);
            union { short s[8]; bf16x8 v8; } u;
            u.s[0] = f2bf(f0.x * 0.125f);
            u.s[1] = f2bf(f0.y * 0.125f);
            u.s[2] = f2bf(f0.z * 0.125f);
            u.s[3] = f2bf(f0.w * 0.125f);
            u.s[4] = f2bf(f1.x * 0.125f);
            u.s[5] = f2bf(f1.y * 0.125f);
            u.s[6] = f2bf(f1.z * 0.125f);
            u.s[7] = f2bf(f1.w * 0.125f);
            qf[qh][kc] = u.v8;
        }

    f32x4 oacc[2][4];  // [qh][dtile]
#pragma unroll
    for (int qh = 0; qh < 2; ++qh)
#pragma unroll
        for (int dt = 0; dt < 4; ++dt) oacc[qh][dt] = (f32x4){0.f, 0.f, 0.f, 0.f};
    float mrun[2][4], lrun[2][4];
#pragma unroll
    for (int qh = 0; qh < 2; ++qh)
#pragma unroll
        for (int r = 0; r < 4; ++r) { mrun[qh][r] = -1e30f; lrun[qh][r] = 0.f; }

    // staging indices: thread -> one row-quarter of the 64x64 tile
    const int row = tid >> 2;
    const int cseg = (tid & 3) * 16;

    for (int kt = 0; kt < SEQ / KB; ++kt) {
        const float* kg = k + base + (size_t)(kt * KB + row) * HEAD_DIM + cseg;
        const float* vg = v + base + (size_t)(kt * KB + row) * HEAD_DIM + cseg;
        float4 kf4[4], vf4[4];
#pragma unroll
        for (int i = 0; i < 4; ++i) {
            kf4[i] = *(const float4*)(kg + 4 * i);
            vf4[i] = *(const float4*)(vg + 4 * i);
        }
        __syncthreads();  // previous iteration's LDS reads complete
        {
            union { short s[8]; bf16x8 v8; } u;
            u.s[0] = f2bf(kf4[0].x); u.s[1] = f2bf(kf4[0].y);
            u.s[2] = f2bf(kf4[0].z); u.s[3] = f2bf(kf4[0].w);
            u.s[4] = f2bf(kf4[1].x); u.s[5] = f2bf(kf4[1].y);
            u.s[6] = f2bf(kf4[1].z); u.s[7] = f2bf(kf4[1].w);
            *(bf16x8*)&Ks[row][cseg] = u.v8;
            u.s[0] = f2bf(kf4[2].x); u.s[1] = f2bf(kf4[2].y);
            u.s[2] = f2bf(kf4[2].z); u.s[3] = f2bf(kf4[2].w);
            u.s[4] = f2bf(kf4[3].x); u.s[5] = f2bf(kf4[3].y);
            u.s[6] = f2bf(kf4[3].z); u.s[7] = f2bf(kf4[3].w);
            *(bf16x8*)&Ks[row][cseg + 8] = u.v8;
        }
#pragma unroll
        for (int i = 0; i < 4; ++i) {
            Vt[cseg + 4 * i + 0][row] = f2bf(vf4[i].x);
            Vt[cseg + 4 * i + 1][row] = f2bf(vf4[i].y);
            Vt[cseg + 4 * i + 2][row] = f2bf(vf4[i].z);
            Vt[cseg + 4 * i + 3][row] = f2bf(vf4[i].w);
        }
        __syncthreads();

        // ---- S = Q K^T (16x16x32 MFMA; D: col=k-idx=a, row=q=g*4+r) ----
        f32x4 sacc[2][4];  // [qh][ktile16]
#pragma unroll
        for (int qh = 0; qh < 2; ++qh)
#pragma unroll
            for (int t4 = 0; t4 < 4; ++t4) sacc[qh][t4] = (f32x4){0.f, 0.f, 0.f, 0.f};
#pragma unroll
        for (int kc = 0; kc < 2; ++kc)
#pragma unroll
            for (int t4 = 0; t4 < 4; ++t4) {
                bf16x8 kf = *(const bf16x8*)&Ks[t4 * 16 + a][kc * 32 + g * 8];
                sacc[0][t4] = __builtin_amdgcn_mfma_f32_16x16x32_bf16(qf[0][kc], kf, sacc[0][t4], 0, 0, 0);
                sacc[1][t4] = __builtin_amdgcn_mfma_f32_16x16x32_bf16(qf[1][kc], kf, sacc[1][t4], 0, 0, 0);
            }

        // ---- online softmax (wave-parallel; k spread over t4 and 16 lanes) ----
#pragma unroll
        for (int qh = 0; qh < 2; ++qh) {
            float tmax[4];
#pragma unroll
            for (int r = 0; r < 4; ++r)
                tmax[r] = fmaxf(fmaxf(sacc[qh][0][r], sacc[qh][1][r]),
                                fmaxf(sacc[qh][2][r], sacc[qh][3][r]));
#pragma unroll
            for (int m = 1; m <= 8; m <<= 1)
#pragma unroll
                for (int r = 0; r < 4; ++r)
                    tmax[r] = fmaxf(tmax[r], __shfl_xor(tmax[r], m, 64));
            float psum[4];
#pragma unroll
            for (int r = 0; r < 4; ++r) {
                const float mnew = fmaxf(mrun[qh][r], tmax[r]);
                const float c = __expf(mrun[qh][r] - mnew);
                mrun[qh][r] = mnew;
                lrun[qh][r] *= c;
#pragma unroll
                for (int dt = 0; dt < 4; ++dt) oacc[qh][dt][r] *= c;
                psum[r] = 0.f;
#pragma unroll
                for (int t4 = 0; t4 < 4; ++t4) {
                    const float p = __expf(sacc[qh][t4][r] - mnew);
                    psum[r] += p;
                    Ps[wid][qh * 16 + g * 4 + r][t4 * 16 + a] = f2bf(p);
                }
            }
#pragma unroll
            for (int m = 1; m <= 8; m <<= 1)
#pragma unroll
                for (int r = 0; r < 4; ++r)
                    psum[r] += __shfl_xor(psum[r], m, 64);
#pragma unroll
            for (int r = 0; r < 4; ++r) lrun[qh][r] += psum[r];
        }

        // ---- O += P V (P via per-wave LDS; V from transposed tile) ----
#pragma unroll
        for (int kc = 0; kc < 2; ++kc) {
            bf16x8 pf0 = *(const bf16x8*)&Ps[wid][a][kc * 32 + g * 8];
            bf16x8 pf1 = *(const bf16x8*)&Ps[wid][16 + a][kc * 32 + g * 8];
#pragma unroll
            for (int dt = 0; dt < 4; ++dt) {
                bf16x8 vf = *(const bf16x8*)&Vt[dt * 16 + a][kc * 32 + g * 8];
                oacc[0][dt] = __builtin_amdgcn_mfma_f32_16x16x32_bf16(pf0, vf, oacc[0][dt], 0, 0, 0);
                oacc[1][dt] = __builtin_amdgcn_mfma_f32_16x16x32_bf16(pf1, vf, oacc[1][dt], 0, 0, 0);
            }
        }
    }

    // ---- normalize + write to ao [B,S,D] ----
    const int b = bh >> 4;
    const int h = bh & 15;
#pragma unroll
    for (int qh = 0; qh < 2; ++qh)
#pragma unroll
        for (int r = 0; r < 4; ++r) {
            const float inv = 1.f / lrun[qh][r];
            const int s = q0w + qh * 16 + g * 4 + r;
            float* dst = ao + ((size_t)b * SEQ + s) * D_MODEL + h * HEAD_DIM;
#pragma unroll
            for (int dt = 0; dt < 4; ++dt)
                dst[dt * 16 + a] = oacc[qh][dt][r] * inv;
        }
}

extern "C" void kernel_launch(void* const* d_in, const int* in_sizes, int n_in,
                              void* d_out, int out_size, void* d_ws, size_t ws_size,
                              hipStream_t stream) {
    const float* x  = (const float*)d_in[0];
    const float* wq = (const float*)d_in[1];
    const float* bq = (const float*)d_in[2];
    const float* wk = (const float*)d_in[3];
    const float* bk = (const float*)d_in[4];
    const float* wv = (const float*)d_in[5];
    const float* bv = (const float*)d_in[6];
    const float* wo = (const float*)d_in[7];
    const float* bo = (const float*)d_in[8];
    float* out = (float*)d_out;

    const size_t PER = (size_t)BATCH * NHEAD * SEQ * HEAD_DIM;
    float* qb = (float*)d_ws;
    float* kb = qb + PER;
    float* vb = kb + PER;
    float* ao = vb + PER;

    dim3 gblock(256);
    dim3 ggrid(D_MODEL / BN, NROWS / BM);

    gemm_kernel<true><<<ggrid, gblock, 0, stream>>>(x, wq, bq, qb);
    gemm_kernel<true><<<ggrid, gblock, 0, stream>>>(x, wk, bk, kb);
    gemm_kernel<true><<<ggrid, gblock, 0, stream>>>(x, wv, bv, vb);

    attn_mfma_kernel<<<dim3(512), dim3(256), 0, stream>>>(qb, kb, vb, ao);

    gemm_kernel<false><<<ggrid, gblock, 0, stream>>>(ao, wo, bo, out);
}

// Round 3
// 229.158 us; speedup vs baseline: 7.4562x; 2.9881x over previous
//
#include <hip/hip_runtime.h>
#include <hip/hip_bf16.h>

#define D_MODEL 1024
#define NHEAD 16
#define HEAD_DIM 64
#define BATCH 2
#define SEQ 2048
#define NROWS 4096

typedef __attribute__((ext_vector_type(8))) short bf16x8;
typedef __attribute__((ext_vector_type(4))) float f32x4;

__device__ __forceinline__ short f2bf(float f) {
    __hip_bfloat16 h = __float2bfloat16(f);
    return __builtin_bit_cast(short, h);
}
__device__ __forceinline__ float bf2f(short s) {
    unsigned u = ((unsigned)(unsigned short)s) << 16;
    return __builtin_bit_cast(float, u);
}

// ---------------- x fp32 -> bf16 (same layout) ----------------
__global__ __launch_bounds__(256) void xconv_kernel(const float* __restrict__ x,
                                                    short* __restrict__ xb) {
    const int i = (blockIdx.x * 256 + threadIdx.x) * 8;
    float4 f0 = *(const float4*)(x + i);
    float4 f1 = *(const float4*)(x + i + 4);
    union { short s[8]; bf16x8 v; } u;
    u.s[0] = f2bf(f0.x); u.s[1] = f2bf(f0.y); u.s[2] = f2bf(f0.z); u.s[3] = f2bf(f0.w);
    u.s[4] = f2bf(f1.x); u.s[5] = f2bf(f1.y); u.s[6] = f2bf(f1.z); u.s[7] = f2bf(f1.w);
    *(bf16x8*)(xb + i) = u.v;
}

// ---------------- weight fp32 [k][n] -> bf16 transposed [n][k] (+lo) ----------------
template <bool SPLIT>
__global__ __launch_bounds__(256) void wconv_kernel(const float* __restrict__ s0,
                                                    const float* __restrict__ s1,
                                                    const float* __restrict__ s2,
                                                    short* __restrict__ d0,
                                                    short* __restrict__ d1,
                                                    short* __restrict__ d2,
                                                    short* __restrict__ dlo) {
    __shared__ float t[32][33];
    const float* src = blockIdx.z == 0 ? s0 : blockIdx.z == 1 ? s1 : s2;
    short* dst = blockIdx.z == 0 ? d0 : blockIdx.z == 1 ? d1 : d2;
    const int nb = blockIdx.x * 32, kb = blockIdx.y * 32;
    const int tx = threadIdx.x & 31, ty = threadIdx.x >> 5;
#pragma unroll
    for (int i = 0; i < 4; ++i)
        t[ty * 4 + i][tx] = src[(size_t)(kb + ty * 4 + i) * D_MODEL + nb + tx];
    __syncthreads();
#pragma unroll
    for (int i = 0; i < 4; ++i) {
        const float f = t[tx][ty * 4 + i];
        const short hi = f2bf(f);
        const size_t o = (size_t)(nb + ty * 4 + i) * D_MODEL + kb + tx;
        dst[o] = hi;
        if (SPLIT) dlo[o] = f2bf(f - bf2f(hi));
    }
}

// ---------------- fused QKV GEMM (bf16 MFMA) ----------------
// xb [4096][1024] bf16; wT [n=1024][k=1024] bf16; out -> [B,H,S,Dh] bf16.
// Tile 64(M) x 128(N), BK=32, 4 waves, wave = 32x64.
__global__ __launch_bounds__(256) void qkv_gemm(const short* __restrict__ xb,
                                                const short* __restrict__ wqT,
                                                const short* __restrict__ wkT,
                                                const short* __restrict__ wvT,
                                                const float* __restrict__ bq,
                                                const float* __restrict__ bk,
                                                const float* __restrict__ bv,
                                                short* __restrict__ qo,
                                                short* __restrict__ ko,
                                                short* __restrict__ vo) {
    __shared__ short As[64 * 32];
    __shared__ short Bs[128 * 32];

    const int tid = threadIdx.x;
    const int wid = tid >> 6;
    const int lane = tid & 63;
    const int a = lane & 15, g = lane >> 4;
    const int wm = wid >> 1, wn = wid & 1;
    const int bn = blockIdx.x, bm = blockIdx.y, z = blockIdx.z;

    const short* wT = z == 0 ? wqT : z == 1 ? wkT : wvT;
    const float* bias = z == 0 ? bq : z == 1 ? bk : bv;
    short* dst = z == 0 ? qo : z == 1 ? ko : vo;
    const float scale = z == 0 ? 0.125f : 1.0f;

    const int srow = tid >> 2;                 // 0..63
    const int sseg = tid & 3;                  // logical (global) 16B segment
    const int pseg = sseg ^ ((tid >> 3) & 3);  // physical LDS segment (XOR swizzle)

    const short* Ag = xb + (size_t)(bm * 64 + srow) * D_MODEL + sseg * 8;
    const short* Bg0 = wT + (size_t)(bn * 128 + srow) * D_MODEL + sseg * 8;
    const short* Bg1 = Bg0 + (size_t)64 * D_MODEL;

    short* Aw = &As[srow * 32 + pseg * 8];
    short* Bw0 = &Bs[srow * 32 + pseg * 8];
    short* Bw1 = &Bs[(srow + 64) * 32 + pseg * 8];

    f32x4 acc[2][4];
#pragma unroll
    for (int mi = 0; mi < 2; ++mi)
#pragma unroll
        for (int ni = 0; ni < 4; ++ni) acc[mi][ni] = (f32x4){0.f, 0.f, 0.f, 0.f};

    int aoff[2], boff[4];
#pragma unroll
    for (int mi = 0; mi < 2; ++mi) {
        const int row = wm * 32 + mi * 16 + a;
        aoff[mi] = row * 32 + ((g ^ ((row >> 1) & 3)) << 3);
    }
#pragma unroll
    for (int ni = 0; ni < 4; ++ni) {
        const int col = wn * 64 + ni * 16 + a;
        boff[ni] = col * 32 + ((g ^ ((col >> 1) & 3)) << 3);
    }

    for (int k0 = 0; k0 < D_MODEL / 32; ++k0) {
        bf16x8 ra = *(const bf16x8*)(Ag);
        bf16x8 rb0 = *(const bf16x8*)(Bg0);
        bf16x8 rb1 = *(const bf16x8*)(Bg1);
        Ag += 32; Bg0 += 32; Bg1 += 32;
        __syncthreads();
        *(bf16x8*)Aw = ra;
        *(bf16x8*)Bw0 = rb0;
        *(bf16x8*)Bw1 = rb1;
        __syncthreads();
        bf16x8 af[2], bfr[4];
#pragma unroll
        for (int mi = 0; mi < 2; ++mi) af[mi] = *(const bf16x8*)&As[aoff[mi]];
#pragma unroll
        for (int ni = 0; ni < 4; ++ni) bfr[ni] = *(const bf16x8*)&Bs[boff[ni]];
#pragma unroll
        for (int mi = 0; mi < 2; ++mi)
#pragma unroll
            for (int ni = 0; ni < 4; ++ni)
                acc[mi][ni] = __builtin_amdgcn_mfma_f32_16x16x32_bf16(af[mi], bfr[ni], acc[mi][ni], 0, 0, 0);
    }

#pragma unroll
    for (int mi = 0; mi < 2; ++mi) {
        const int mbase = bm * 64 + wm * 32 + mi * 16 + g * 4;
#pragma unroll
        for (int ni = 0; ni < 4; ++ni) {
            const int col = bn * 128 + wn * 64 + ni * 16 + a;
            const int h = col >> 6, d = col & 63;
            const float bb = bias[col];
#pragma unroll
            for (int r = 0; r < 4; ++r) {
                const int m = mbase + r;
                const int b = m >> 11, s = m & 2047;
                dst[(((size_t)(b * NHEAD + h) * SEQ + s) << 6) + d] =
                    f2bf((acc[mi][ni][r] + bb) * scale);
            }
        }
    }
}

// ---------------- output projection, 3-term split bf16 ----------------
__global__ __launch_bounds__(256) void oproj_gemm(const short* __restrict__ aoh,
                                                  const short* __restrict__ aol,
                                                  const short* __restrict__ wTh,
                                                  const short* __restrict__ wTl,
                                                  const float* __restrict__ bo,
                                                  float* __restrict__ out) {
    __shared__ short Ah[64 * 32];
    __shared__ short Al[64 * 32];
    __shared__ short Bh[128 * 32];
    __shared__ short Bl[128 * 32];

    const int tid = threadIdx.x;
    const int wid = tid >> 6;
    const int lane = tid & 63;
    const int a = lane & 15, g = lane >> 4;
    const int wm = wid >> 1, wn = wid & 1;
    const int bn = blockIdx.x, bm = blockIdx.y;

    const int srow = tid >> 2;
    const int sseg = tid & 3;
    const int pseg = sseg ^ ((tid >> 3) & 3);

    const short* Agh = aoh + (size_t)(bm * 64 + srow) * D_MODEL + sseg * 8;
    const short* Agl = aol + (size_t)(bm * 64 + srow) * D_MODEL + sseg * 8;
    const short* Bgh0 = wTh + (size_t)(bn * 128 + srow) * D_MODEL + sseg * 8;
    const short* Bgh1 = Bgh0 + (size_t)64 * D_MODEL;
    const short* Bgl0 = wTl + (size_t)(bn * 128 + srow) * D_MODEL + sseg * 8;
    const short* Bgl1 = Bgl0 + (size_t)64 * D_MODEL;

    const int woff = srow * 32 + pseg * 8;
    const int woff1 = (srow + 64) * 32 + pseg * 8;

    f32x4 acc[2][4];
#pragma unroll
    for (int mi = 0; mi < 2; ++mi)
#pragma unroll
        for (int ni = 0; ni < 4; ++ni) acc[mi][ni] = (f32x4){0.f, 0.f, 0.f, 0.f};

    int aoff[2], boff[4];
#pragma unroll
    for (int mi = 0; mi < 2; ++mi) {
        const int row = wm * 32 + mi * 16 + a;
        aoff[mi] = row * 32 + ((g ^ ((row >> 1) & 3)) << 3);
    }
#pragma unroll
    for (int ni = 0; ni < 4; ++ni) {
        const int col = wn * 64 + ni * 16 + a;
        boff[ni] = col * 32 + ((g ^ ((col >> 1) & 3)) << 3);
    }

    for (int k0 = 0; k0 < D_MODEL / 32; ++k0) {
        bf16x8 rah = *(const bf16x8*)(Agh);
        bf16x8 ral = *(const bf16x8*)(Agl);
        bf16x8 rbh0 = *(const bf16x8*)(Bgh0);
        bf16x8 rbh1 = *(const bf16x8*)(Bgh1);
        bf16x8 rbl0 = *(const bf16x8*)(Bgl0);
        bf16x8 rbl1 = *(const bf16x8*)(Bgl1);
        Agh += 32; Agl += 32; Bgh0 += 32; Bgh1 += 32; Bgl0 += 32; Bgl1 += 32;
        __syncthreads();
        *(bf16x8*)&Ah[woff] = rah;
        *(bf16x8*)&Al[woff] = ral;
        *(bf16x8*)&Bh[woff] = rbh0;
        *(bf16x8*)&Bh[woff1] = rbh1;
        *(bf16x8*)&Bl[woff] = rbl0;
        *(bf16x8*)&Bl[woff1] = rbl1;
        __syncthreads();
        bf16x8 afh[2], afl[2], bfh[4], bfl[4];
#pragma unroll
        for (int mi = 0; mi < 2; ++mi) {
            afh[mi] = *(const bf16x8*)&Ah[aoff[mi]];
            afl[mi] = *(const bf16x8*)&Al[aoff[mi]];
        }
#pragma unroll
        for (int ni = 0; ni < 4; ++ni) {
            bfh[ni] = *(const bf16x8*)&Bh[boff[ni]];
            bfl[ni] = *(const bf16x8*)&Bl[boff[ni]];
        }
#pragma unroll
        for (int mi = 0; mi < 2; ++mi)
#pragma unroll
            for (int ni = 0; ni < 4; ++ni) {
                acc[mi][ni] = __builtin_amdgcn_mfma_f32_16x16x32_bf16(afh[mi], bfh[ni], acc[mi][ni], 0, 0, 0);
                acc[mi][ni] = __builtin_amdgcn_mfma_f32_16x16x32_bf16(afh[mi], bfl[ni], acc[mi][ni], 0, 0, 0);
                acc[mi][ni] = __builtin_amdgcn_mfma_f32_16x16x32_bf16(afl[mi], bfh[ni], acc[mi][ni], 0, 0, 0);
            }
    }

#pragma unroll
    for (int mi = 0; mi < 2; ++mi) {
        const int mbase = bm * 64 + wm * 32 + mi * 16 + g * 4;
#pragma unroll
        for (int ni = 0; ni < 4; ++ni) {
            const int col = bn * 128 + wn * 64 + ni * 16 + a;
            const float bb = bo[col];
#pragma unroll
            for (int r = 0; r < 4; ++r)
                out[(size_t)(mbase + r) * D_MODEL + col] = acc[mi][ni][r] + bb;
        }
    }
}

// ---------------- Flash attention, bf16 MFMA (bf16 in, split bf16 out) ----------------
#define KB 64
#define PITCH 72

__global__ __launch_bounds__(256) void attn_mfma_kernel(const short* __restrict__ q,
                                                        const short* __restrict__ k,
                                                        const short* __restrict__ v,
                                                        short* __restrict__ aoh,
                                                        short* __restrict__ aol) {
    __shared__ short Ks[KB][PITCH];
    __shared__ short Vt[HEAD_DIM][PITCH];
    __shared__ short Ps[4][32][PITCH];

    const int tid = threadIdx.x;
    const int wid = tid >> 6;
    const int lane = tid & 63;
    const int a = lane & 15;
    const int g = lane >> 4;

    const int bid = blockIdx.x;
    const int bh = bid >> 4;
    const int qc = bid & 15;
    const int q0w = qc * 128 + wid * 32;

    const size_t base = (size_t)bh * SEQ * HEAD_DIM;

    // Q fragments (q already scaled by 1/8 in qkv_gemm)
    bf16x8 qf[2][2];
#pragma unroll
    for (int qh = 0; qh < 2; ++qh)
#pragma unroll
        for (int kc = 0; kc < 2; ++kc)
            qf[qh][kc] = *(const bf16x8*)(q + base + (size_t)(q0w + qh * 16 + a) * HEAD_DIM + kc * 32 + g * 8);

    f32x4 oacc[2][4];
#pragma unroll
    for (int qh = 0; qh < 2; ++qh)
#pragma unroll
        for (int dt = 0; dt < 4; ++dt) oacc[qh][dt] = (f32x4){0.f, 0.f, 0.f, 0.f};
    float mrun[2][4], lrun[2][4];
#pragma unroll
    for (int qh = 0; qh < 2; ++qh)
#pragma unroll
        for (int r = 0; r < 4; ++r) { mrun[qh][r] = -1e30f; lrun[qh][r] = 0.f; }

    const int row = tid >> 2;
    const int sc = (tid & 3) * 8;

    for (int kt = 0; kt < SEQ / KB; ++kt) {
        const short* kg = k + base + (size_t)(kt * KB + row) * HEAD_DIM + sc;
        const short* vg = v + base + (size_t)(kt * KB + row) * HEAD_DIM + sc;
        bf16x8 k0 = *(const bf16x8*)kg;
        bf16x8 k1 = *(const bf16x8*)(kg + 32);
        bf16x8 v0 = *(const bf16x8*)vg;
        bf16x8 v1 = *(const bf16x8*)(vg + 32);
        __syncthreads();
        *(bf16x8*)&Ks[row][sc] = k0;
        *(bf16x8*)&Ks[row][sc + 32] = k1;
#pragma unroll
        for (int j = 0; j < 8; ++j) {
            Vt[sc + j][row] = v0[j];
            Vt[sc + 32 + j][row] = v1[j];
        }
        __syncthreads();

        f32x4 sacc[2][4];
#pragma unroll
        for (int qh = 0; qh < 2; ++qh)
#pragma unroll
            for (int t4 = 0; t4 < 4; ++t4) sacc[qh][t4] = (f32x4){0.f, 0.f, 0.f, 0.f};
#pragma unroll
        for (int kc = 0; kc < 2; ++kc)
#pragma unroll
            for (int t4 = 0; t4 < 4; ++t4) {
                bf16x8 kf = *(const bf16x8*)&Ks[t4 * 16 + a][kc * 32 + g * 8];
                sacc[0][t4] = __builtin_amdgcn_mfma_f32_16x16x32_bf16(qf[0][kc], kf, sacc[0][t4], 0, 0, 0);
                sacc[1][t4] = __builtin_amdgcn_mfma_f32_16x16x32_bf16(qf[1][kc], kf, sacc[1][t4], 0, 0, 0);
            }

#pragma unroll
        for (int qh = 0; qh < 2; ++qh) {
            float tmax[4];
#pragma unroll
            for (int r = 0; r < 4; ++r)
                tmax[r] = fmaxf(fmaxf(sacc[qh][0][r], sacc[qh][1][r]),
                                fmaxf(sacc[qh][2][r], sacc[qh][3][r]));
#pragma unroll
            for (int m = 1; m <= 8; m <<= 1)
#pragma unroll
                for (int r = 0; r < 4; ++r)
                    tmax[r] = fmaxf(tmax[r], __shfl_xor(tmax[r], m, 64));
            float psum[4];
#pragma unroll
            for (int r = 0; r < 4; ++r) {
                const float mnew = fmaxf(mrun[qh][r], tmax[r]);
                const float c = __expf(mrun[qh][r] - mnew);
                mrun[qh][r] = mnew;
                lrun[qh][r] *= c;
#pragma unroll
                for (int dt = 0; dt < 4; ++dt) oacc[qh][dt][r] *= c;
                psum[r] = 0.f;
#pragma unroll
                for (int t4 = 0; t4 < 4; ++t4) {
                    const float p = __expf(sacc[qh][t4][r] - mnew);
                    psum[r] += p;
                    Ps[wid][qh * 16 + g * 4 + r][t4 * 16 + a] = f2bf(p);
                }
            }
#pragma unroll
            for (int m = 1; m <= 8; m <<= 1)
#pragma unroll
                for (int r = 0; r < 4; ++r)
                    psum[r] += __shfl_xor(psum[r], m, 64);
#pragma unroll
            for (int r = 0; r < 4; ++r) lrun[qh][r] += psum[r];
        }

#pragma unroll
        for (int kc = 0; kc < 2; ++kc) {
            bf16x8 pf0 = *(const bf16x8*)&Ps[wid][a][kc * 32 + g * 8];
            bf16x8 pf1 = *(const bf16x8*)&Ps[wid][16 + a][kc * 32 + g * 8];
#pragma unroll
            for (int dt = 0; dt < 4; ++dt) {
                bf16x8 vf = *(const bf16x8*)&Vt[dt * 16 + a][kc * 32 + g * 8];
                oacc[0][dt] = __builtin_amdgcn_mfma_f32_16x16x32_bf16(pf0, vf, oacc[0][dt], 0, 0, 0);
                oacc[1][dt] = __builtin_amdgcn_mfma_f32_16x16x32_bf16(pf1, vf, oacc[1][dt], 0, 0, 0);
            }
        }
    }

    const int b = bh >> 4;
    const int h = bh & 15;
#pragma unroll
    for (int qh = 0; qh < 2; ++qh)
#pragma unroll
        for (int r = 0; r < 4; ++r) {
            const float inv = 1.f / lrun[qh][r];
            const int s = q0w + qh * 16 + g * 4 + r;
            const size_t rb = ((size_t)b * SEQ + s) * D_MODEL + h * HEAD_DIM;
#pragma unroll
            for (int dt = 0; dt < 4; ++dt) {
                const float o = oacc[qh][dt][r] * inv;
                const short hi = f2bf(o);
                aoh[rb + dt * 16 + a] = hi;
                aol[rb + dt * 16 + a] = f2bf(o - bf2f(hi));
            }
        }
}

extern "C" void kernel_launch(void* const* d_in, const int* in_sizes, int n_in,
                              void* d_out, int out_size, void* d_ws, size_t ws_size,
                              hipStream_t stream) {
    const float* x  = (const float*)d_in[0];
    const float* wq = (const float*)d_in[1];
    const float* bq = (const float*)d_in[2];
    const float* wk = (const float*)d_in[3];
    const float* bk = (const float*)d_in[4];
    const float* wv = (const float*)d_in[5];
    const float* bv = (const float*)d_in[6];
    const float* wo = (const float*)d_in[7];
    const float* bo = (const float*)d_in[8];
    float* out = (float*)d_out;

    short* ws   = (short*)d_ws;
    short* xb   = ws;                   // 4096*1024
    short* wqT  = xb + 4194304;         // 1024*1024 each
    short* wkT  = wqT + 1048576;
    short* wvT  = wkT + 1048576;
    short* woTh = wvT + 1048576;
    short* woTl = woTh + 1048576;
    short* qb   = woTl + 1048576;       // 4194304 each
    short* kb   = qb + 4194304;
    short* vb   = kb + 4194304;
    short* aoh  = vb + 4194304;
    short* aol  = aoh + 4194304;

    xconv_kernel<<<dim3(2048), dim3(256), 0, stream>>>(x, xb);
    wconv_kernel<false><<<dim3(32, 32, 3), dim3(256), 0, stream>>>(wq, wk, wv, wqT, wkT, wvT, nullptr);
    wconv_kernel<true><<<dim3(32, 32, 1), dim3(256), 0, stream>>>(wo, nullptr, nullptr, woTh, nullptr, nullptr, woTl);

    qkv_gemm<<<dim3(8, 64, 3), dim3(256), 0, stream>>>(xb, wqT, wkT, wvT, bq, bk, bv, qb, kb, vb);

    attn_mfma_kernel<<<dim3(512), dim3(256), 0, stream>>>(qb, kb, vb, aoh, aol);

    oproj_gemm<<<dim3(8, 64), dim3(256), 0, stream>>>(aoh, aol, woTh, woTl, bo, out);
}

// Round 4
// 164.191 us; speedup vs baseline: 10.4064x; 1.3957x over previous
//
#include <hip/hip_runtime.h>
#include <hip/hip_bf16.h>

#define D_MODEL 1024
#define NHEAD 16
#define HEAD_DIM 64
#define BATCH 2
#define SEQ 2048
#define NROWS 4096

typedef __attribute__((ext_vector_type(8))) short bf16x8;
typedef __attribute__((ext_vector_type(4))) short bf16x4;
typedef __attribute__((ext_vector_type(4))) float f32x4;

__device__ __forceinline__ short f2bf(float f) {
    __hip_bfloat16 h = __float2bfloat16(f);
    return __builtin_bit_cast(short, h);
}
__device__ __forceinline__ float bf2f(short s) {
    unsigned u = ((unsigned)(unsigned short)s) << 16;
    return __builtin_bit_cast(float, u);
}
// XOR swizzle for 128-byte LDS rows: spreads each column across 8 16B slots.
__device__ __forceinline__ int swz128(int row, int byteoff) {
    return (row * 128 + byteoff) ^ ((row & 7) << 4);
}

// ---------------- x fp32 -> bf16 ----------------
__global__ __launch_bounds__(256) void xconv_kernel(const float* __restrict__ x,
                                                    short* __restrict__ xb) {
    const int i = (blockIdx.x * 256 + threadIdx.x) * 8;
    float4 f0 = *(const float4*)(x + i);
    float4 f1 = *(const float4*)(x + i + 4);
    union { short s[8]; bf16x8 v; } u;
    u.s[0] = f2bf(f0.x); u.s[1] = f2bf(f0.y); u.s[2] = f2bf(f0.z); u.s[3] = f2bf(f0.w);
    u.s[4] = f2bf(f1.x); u.s[5] = f2bf(f1.y); u.s[6] = f2bf(f1.z); u.s[7] = f2bf(f1.w);
    *(bf16x8*)(xb + i) = u.v;
}

// ---------------- weight fp32 [k][n] -> bf16 transposed [n][k] (+lo) ----------------
template <bool SPLIT>
__global__ __launch_bounds__(256) void wconv_kernel(const float* __restrict__ s0,
                                                    const float* __restrict__ s1,
                                                    const float* __restrict__ s2,
                                                    short* __restrict__ d0,
                                                    short* __restrict__ d1,
                                                    short* __restrict__ d2,
                                                    short* __restrict__ dlo) {
    __shared__ float t[32][33];
    const float* src = blockIdx.z == 0 ? s0 : blockIdx.z == 1 ? s1 : s2;
    short* dst = blockIdx.z == 0 ? d0 : blockIdx.z == 1 ? d1 : d2;
    const int nb = blockIdx.x * 32, kb = blockIdx.y * 32;
    const int tx = threadIdx.x & 31, ty = threadIdx.x >> 5;
#pragma unroll
    for (int i = 0; i < 4; ++i)
        t[ty * 4 + i][tx] = src[(size_t)(kb + ty * 4 + i) * D_MODEL + nb + tx];
    __syncthreads();
#pragma unroll
    for (int i = 0; i < 4; ++i) {
        const float f = t[tx][ty * 4 + i];
        const short hi = f2bf(f);
        const size_t o = (size_t)(nb + ty * 4 + i) * D_MODEL + kb + tx;
        dst[o] = hi;
        if (SPLIT) dlo[o] = f2bf(f - bf2f(hi));
    }
}

// ---------------- fused QKV GEMM (bf16 MFMA) ----------------
// q,k -> [B,H,S,Dh]; v -> TRANSPOSED [B,H,Dh,S] (for attn's PV B-operand).
__global__ __launch_bounds__(256) void qkv_gemm(const short* __restrict__ xb,
                                                const short* __restrict__ wqT,
                                                const short* __restrict__ wkT,
                                                const short* __restrict__ wvT,
                                                const float* __restrict__ bq,
                                                const float* __restrict__ bk,
                                                const float* __restrict__ bv,
                                                short* __restrict__ qo,
                                                short* __restrict__ ko,
                                                short* __restrict__ vo) {
    __shared__ short As[64 * 32];
    __shared__ short Bs[128 * 32];

    const int tid = threadIdx.x;
    const int wid = tid >> 6;
    const int lane = tid & 63;
    const int a = lane & 15, g = lane >> 4;
    const int wm = wid >> 1, wn = wid & 1;
    const int bn = blockIdx.x, bm = blockIdx.y, z = blockIdx.z;

    const short* wT = z == 0 ? wqT : z == 1 ? wkT : wvT;
    const float* bias = z == 0 ? bq : z == 1 ? bk : bv;
    short* dst = z == 0 ? qo : z == 1 ? ko : vo;
    const float scale = z == 0 ? 0.125f : 1.0f;

    const int srow = tid >> 2;
    const int sseg = tid & 3;
    const int pseg = sseg ^ ((tid >> 3) & 3);

    const short* Ag = xb + (size_t)(bm * 64 + srow) * D_MODEL + sseg * 8;
    const short* Bg0 = wT + (size_t)(bn * 128 + srow) * D_MODEL + sseg * 8;
    const short* Bg1 = Bg0 + (size_t)64 * D_MODEL;

    short* Aw = &As[srow * 32 + pseg * 8];
    short* Bw0 = &Bs[srow * 32 + pseg * 8];
    short* Bw1 = &Bs[(srow + 64) * 32 + pseg * 8];

    f32x4 acc[2][4];
#pragma unroll
    for (int mi = 0; mi < 2; ++mi)
#pragma unroll
        for (int ni = 0; ni < 4; ++ni) acc[mi][ni] = (f32x4){0.f, 0.f, 0.f, 0.f};

    int aoff[2], boff[4];
#pragma unroll
    for (int mi = 0; mi < 2; ++mi) {
        const int row = wm * 32 + mi * 16 + a;
        aoff[mi] = row * 32 + ((g ^ ((row >> 1) & 3)) << 3);
    }
#pragma unroll
    for (int ni = 0; ni < 4; ++ni) {
        const int col = wn * 64 + ni * 16 + a;
        boff[ni] = col * 32 + ((g ^ ((col >> 1) & 3)) << 3);
    }

    for (int k0 = 0; k0 < D_MODEL / 32; ++k0) {
        bf16x8 ra = *(const bf16x8*)(Ag);
        bf16x8 rb0 = *(const bf16x8*)(Bg0);
        bf16x8 rb1 = *(const bf16x8*)(Bg1);
        Ag += 32; Bg0 += 32; Bg1 += 32;
        __syncthreads();
        *(bf16x8*)Aw = ra;
        *(bf16x8*)Bw0 = rb0;
        *(bf16x8*)Bw1 = rb1;
        __syncthreads();
        bf16x8 af[2], bfr[4];
#pragma unroll
        for (int mi = 0; mi < 2; ++mi) af[mi] = *(const bf16x8*)&As[aoff[mi]];
#pragma unroll
        for (int ni = 0; ni < 4; ++ni) bfr[ni] = *(const bf16x8*)&Bs[boff[ni]];
#pragma unroll
        for (int mi = 0; mi < 2; ++mi)
#pragma unroll
            for (int ni = 0; ni < 4; ++ni)
                acc[mi][ni] = __builtin_amdgcn_mfma_f32_16x16x32_bf16(af[mi], bfr[ni], acc[mi][ni], 0, 0, 0);
    }

#pragma unroll
    for (int mi = 0; mi < 2; ++mi) {
        const int mbase = bm * 64 + wm * 32 + mi * 16 + g * 4;
#pragma unroll
        for (int ni = 0; ni < 4; ++ni) {
            const int col = bn * 128 + wn * 64 + ni * 16 + a;
            const int h = col >> 6, d = col & 63;
            const float bb = bias[col];
            if (z == 2) {
                // V transposed: vo[b,h][d][s], 4 consecutive s -> one 8B store
                const int b = mbase >> 11, s = mbase & 2047;
                union { short s4[4]; bf16x4 v; } u;
#pragma unroll
                for (int r = 0; r < 4; ++r) u.s4[r] = f2bf(acc[mi][ni][r] + bb);
                *(bf16x4*)(vo + (((size_t)(b * NHEAD + h) * HEAD_DIM + d) << 11) + s) = u.v;
            } else {
#pragma unroll
                for (int r = 0; r < 4; ++r) {
                    const int m = mbase + r;
                    const int b = m >> 11, s = m & 2047;
                    dst[(((size_t)(b * NHEAD + h) * SEQ + s) << 6) + d] =
                        f2bf((acc[mi][ni][r] + bb) * scale);
                }
            }
        }
    }
}

// ---------------- output projection, 3-term split bf16 ----------------
__global__ __launch_bounds__(256) void oproj_gemm(const short* __restrict__ aoh,
                                                  const short* __restrict__ aol,
                                                  const short* __restrict__ wTh,
                                                  const short* __restrict__ wTl,
                                                  const float* __restrict__ bo,
                                                  float* __restrict__ out) {
    __shared__ short Ah[64 * 32];
    __shared__ short Al[64 * 32];
    __shared__ short Bh[128 * 32];
    __shared__ short Bl[128 * 32];

    const int tid = threadIdx.x;
    const int wid = tid >> 6;
    const int lane = tid & 63;
    const int a = lane & 15, g = lane >> 4;
    const int wm = wid >> 1, wn = wid & 1;
    const int bn = blockIdx.x, bm = blockIdx.y;

    const int srow = tid >> 2;
    const int sseg = tid & 3;
    const int pseg = sseg ^ ((tid >> 3) & 3);

    const short* Agh = aoh + (size_t)(bm * 64 + srow) * D_MODEL + sseg * 8;
    const short* Agl = aol + (size_t)(bm * 64 + srow) * D_MODEL + sseg * 8;
    const short* Bgh0 = wTh + (size_t)(bn * 128 + srow) * D_MODEL + sseg * 8;
    const short* Bgh1 = Bgh0 + (size_t)64 * D_MODEL;
    const short* Bgl0 = wTl + (size_t)(bn * 128 + srow) * D_MODEL + sseg * 8;
    const short* Bgl1 = Bgl0 + (size_t)64 * D_MODEL;

    const int woff = srow * 32 + pseg * 8;
    const int woff1 = (srow + 64) * 32 + pseg * 8;

    f32x4 acc[2][4];
#pragma unroll
    for (int mi = 0; mi < 2; ++mi)
#pragma unroll
        for (int ni = 0; ni < 4; ++ni) acc[mi][ni] = (f32x4){0.f, 0.f, 0.f, 0.f};

    int aoff[2], boff[4];
#pragma unroll
    for (int mi = 0; mi < 2; ++mi) {
        const int row = wm * 32 + mi * 16 + a;
        aoff[mi] = row * 32 + ((g ^ ((row >> 1) & 3)) << 3);
    }
#pragma unroll
    for (int ni = 0; ni < 4; ++ni) {
        const int col = wn * 64 + ni * 16 + a;
        boff[ni] = col * 32 + ((g ^ ((col >> 1) & 3)) << 3);
    }

    for (int k0 = 0; k0 < D_MODEL / 32; ++k0) {
        bf16x8 rah = *(const bf16x8*)(Agh);
        bf16x8 ral = *(const bf16x8*)(Agl);
        bf16x8 rbh0 = *(const bf16x8*)(Bgh0);
        bf16x8 rbh1 = *(const bf16x8*)(Bgh1);
        bf16x8 rbl0 = *(const bf16x8*)(Bgl0);
        bf16x8 rbl1 = *(const bf16x8*)(Bgl1);
        Agh += 32; Agl += 32; Bgh0 += 32; Bgh1 += 32; Bgl0 += 32; Bgl1 += 32;
        __syncthreads();
        *(bf16x8*)&Ah[woff] = rah;
        *(bf16x8*)&Al[woff] = ral;
        *(bf16x8*)&Bh[woff] = rbh0;
        *(bf16x8*)&Bh[woff1] = rbh1;
        *(bf16x8*)&Bl[woff] = rbl0;
        *(bf16x8*)&Bl[woff1] = rbl1;
        __syncthreads();
        bf16x8 afh[2], afl[2], bfh[4], bfl[4];
#pragma unroll
        for (int mi = 0; mi < 2; ++mi) {
            afh[mi] = *(const bf16x8*)&Ah[aoff[mi]];
            afl[mi] = *(const bf16x8*)&Al[aoff[mi]];
        }
#pragma unroll
        for (int ni = 0; ni < 4; ++ni) {
            bfh[ni] = *(const bf16x8*)&Bh[boff[ni]];
            bfl[ni] = *(const bf16x8*)&Bl[boff[ni]];
        }
#pragma unroll
        for (int mi = 0; mi < 2; ++mi)
#pragma unroll
            for (int ni = 0; ni < 4; ++ni) {
                acc[mi][ni] = __builtin_amdgcn_mfma_f32_16x16x32_bf16(afh[mi], bfh[ni], acc[mi][ni], 0, 0, 0);
                acc[mi][ni] = __builtin_amdgcn_mfma_f32_16x16x32_bf16(afh[mi], bfl[ni], acc[mi][ni], 0, 0, 0);
                acc[mi][ni] = __builtin_amdgcn_mfma_f32_16x16x32_bf16(afl[mi], bfh[ni], acc[mi][ni], 0, 0, 0);
            }
    }

#pragma unroll
    for (int mi = 0; mi < 2; ++mi) {
        const int mbase = bm * 64 + wm * 32 + mi * 16 + g * 4;
#pragma unroll
        for (int ni = 0; ni < 4; ++ni) {
            const int col = bn * 128 + wn * 64 + ni * 16 + a;
            const float bb = bo[col];
#pragma unroll
            for (int r = 0; r < 4; ++r)
                out[(size_t)(mbase + r) * D_MODEL + col] = acc[mi][ni][r] + bb;
        }
    }
}

// ---------------- Flash attention v2: swapped QK^T, XOR-swizzled LDS ----------------
// q,k in [B,H,S,64]; vT in [B,H,64,S]; out split bf16 to aoh/aol [B,S,D].
#define ATHR 8.0f

__global__ __launch_bounds__(256) void attn2_kernel(const short* __restrict__ q,
                                                    const short* __restrict__ k,
                                                    const short* __restrict__ vT,
                                                    short* __restrict__ aoh,
                                                    short* __restrict__ aol) {
    __shared__ __align__(16) short Ks[64 * 64];       // [kv][dk], swizzled 128B rows
    __shared__ __align__(16) short Vs[64 * 64];       // [d][kv], swizzled
    __shared__ __align__(16) short Ps[4][32 * 64];    // per-wave [q][kv], swizzled

    const int tid = threadIdx.x;
    const int wid = tid >> 6;
    const int lane = tid & 63;
    const int a = lane & 15;
    const int g = lane >> 4;

    const int bh = blockIdx.x >> 4;
    const int qc = blockIdx.x & 15;
    const int q0w = qc * 128 + wid * 32;

    const size_t base = (size_t)bh * SEQ * HEAD_DIM;
    char* const Kb = (char*)Ks;
    char* const Vb = (char*)Vs;
    char* const Pb = (char*)&Ps[wid][0];

    // Q fragments (B-operand): lane (a,g) holds Q[q0w+qt*16+a][kc*32+g*8 ..+7]
    bf16x8 qf[2][2];
#pragma unroll
    for (int qt = 0; qt < 2; ++qt)
#pragma unroll
        for (int kc = 0; kc < 2; ++kc)
            qf[qt][kc] = *(const bf16x8*)(q + base + (size_t)(q0w + qt * 16 + a) * HEAD_DIM + kc * 32 + g * 8);

    f32x4 oacc[2][4];
#pragma unroll
    for (int qt = 0; qt < 2; ++qt)
#pragma unroll
        for (int dt = 0; dt < 4; ++dt) oacc[qt][dt] = (f32x4){0.f, 0.f, 0.f, 0.f};
    float mrun[2] = {-1e30f, -1e30f};
    float lrun[2] = {0.f, 0.f};

    // staging: 256 threads, rows 0..31 (+32), 8 x 16B segments per 128B row
    const int srow = tid >> 3;
    const int sseg = tid & 7;

    const short* kg = k + base + (size_t)srow * HEAD_DIM + sseg * 8;
    const short* vg = vT + base + (size_t)srow * SEQ + sseg * 8;
    bf16x8 kr0 = *(const bf16x8*)(kg);
    bf16x8 kr1 = *(const bf16x8*)(kg + 32 * HEAD_DIM);
    bf16x8 vr0 = *(const bf16x8*)(vg);
    bf16x8 vr1 = *(const bf16x8*)(vg + 32 * SEQ);

    for (int kt = 0; kt < SEQ / 64; ++kt) {
        __syncthreads();  // previous tile's LDS reads complete
        *(bf16x8*)(Kb + swz128(srow, sseg * 16)) = kr0;
        *(bf16x8*)(Kb + swz128(srow + 32, sseg * 16)) = kr1;
        *(bf16x8*)(Vb + swz128(srow, sseg * 16)) = vr0;
        *(bf16x8*)(Vb + swz128(srow + 32, sseg * 16)) = vr1;
        __syncthreads();

        if (kt + 1 < SEQ / 64) {  // issue next tile's loads early (hide under compute)
            const short* kg2 = k + base + (size_t)((kt + 1) * 64 + srow) * HEAD_DIM + sseg * 8;
            const short* vg2 = vT + base + (size_t)srow * SEQ + (kt + 1) * 64 + sseg * 8;
            kr0 = *(const bf16x8*)(kg2);
            kr1 = *(const bf16x8*)(kg2 + 32 * HEAD_DIM);
            vr0 = *(const bf16x8*)(vg2);
            vr1 = *(const bf16x8*)(vg2 + 32 * SEQ);
        }

        // ---- S^T = K Q^T : C[row=kv-local g*4+r][col=q-local a] ----
        f32x4 sacc[2][4];
#pragma unroll
        for (int qt = 0; qt < 2; ++qt)
#pragma unroll
            for (int t4 = 0; t4 < 4; ++t4) sacc[qt][t4] = (f32x4){0.f, 0.f, 0.f, 0.f};
#pragma unroll
        for (int t4 = 0; t4 < 4; ++t4)
#pragma unroll
            for (int kc = 0; kc < 2; ++kc) {
                bf16x8 kf = *(const bf16x8*)(Kb + swz128(t4 * 16 + a, kc * 64 + g * 16));
                sacc[0][t4] = __builtin_amdgcn_mfma_f32_16x16x32_bf16(kf, qf[0][kc], sacc[0][t4], 0, 0, 0);
                sacc[1][t4] = __builtin_amdgcn_mfma_f32_16x16x32_bf16(kf, qf[1][kc], sacc[1][t4], 0, 0, 0);
            }

        // ---- online softmax: lane (a,g) owns q-row qt*16+a, scores at kv=t4*16+g*4+r ----
#pragma unroll
        for (int qt = 0; qt < 2; ++qt) {
            float tm = fmaxf(fmaxf(fmaxf(sacc[qt][0][0], sacc[qt][0][1]), fmaxf(sacc[qt][0][2], sacc[qt][0][3])),
                             fmaxf(fmaxf(sacc[qt][1][0], sacc[qt][1][1]), fmaxf(sacc[qt][1][2], sacc[qt][1][3])));
            tm = fmaxf(tm, fmaxf(fmaxf(fmaxf(sacc[qt][2][0], sacc[qt][2][1]), fmaxf(sacc[qt][2][2], sacc[qt][2][3])),
                                 fmaxf(fmaxf(sacc[qt][3][0], sacc[qt][3][1]), fmaxf(sacc[qt][3][2], sacc[qt][3][3]))));
            tm = fmaxf(tm, __shfl_xor(tm, 16, 64));
            tm = fmaxf(tm, __shfl_xor(tm, 32, 64));

            if (__any(tm > mrun[qt] + ATHR)) {  // defer-max: rescale only on real growth
                const float mnew = fmaxf(mrun[qt], tm);
                const float c = __expf(mrun[qt] - mnew);
                lrun[qt] *= c;
                float cb[4];
#pragma unroll
                for (int r = 0; r < 4; ++r) cb[r] = __shfl(c, g * 4 + r, 64);
#pragma unroll
                for (int dt = 0; dt < 4; ++dt)
#pragma unroll
                    for (int r = 0; r < 4; ++r) oacc[qt][dt][r] *= cb[r];
                mrun[qt] = mnew;
            }

            float ps = 0.f;
#pragma unroll
            for (int t4 = 0; t4 < 4; ++t4) {
                union { short s4[4]; bf16x4 v; } u;
#pragma unroll
                for (int r = 0; r < 4; ++r) {
                    const float p = __expf(sacc[qt][t4][r] - mrun[qt]);
                    ps += p;
                    u.s4[r] = f2bf(p);
                }
                *(bf16x4*)(Pb + swz128(qt * 16 + a, t4 * 32 + g * 8)) = u.v;
            }
            ps += __shfl_xor(ps, 16, 64);
            ps += __shfl_xor(ps, 32, 64);
            lrun[qt] += ps;
        }

        // ---- O += P V : A=P rows q, B=V^T rows d ----
        bf16x8 pf[2][2], vf[4][2];
#pragma unroll
        for (int qt = 0; qt < 2; ++qt)
#pragma unroll
            for (int kc = 0; kc < 2; ++kc)
                pf[qt][kc] = *(const bf16x8*)(Pb + swz128(qt * 16 + a, kc * 64 + g * 16));
#pragma unroll
        for (int dt = 0; dt < 4; ++dt)
#pragma unroll
            for (int kc = 0; kc < 2; ++kc)
                vf[dt][kc] = *(const bf16x8*)(Vb + swz128(dt * 16 + a, kc * 64 + g * 16));
#pragma unroll
        for (int qt = 0; qt < 2; ++qt)
#pragma unroll
            for (int dt = 0; dt < 4; ++dt)
#pragma unroll
            for (int kc = 0; kc < 2; ++kc)
                oacc[qt][dt] = __builtin_amdgcn_mfma_f32_16x16x32_bf16(pf[qt][kc], vf[dt][kc], oacc[qt][dt], 0, 0, 0);
    }

    // ---- epilogue: O[q=qt*16+g*4+r][d=dt*16+a], normalize by lrun of that row ----
    const int b = bh >> 4;
    const int h = bh & 15;
#pragma unroll
    for (int qt = 0; qt < 2; ++qt) {
        const float inv = 1.f / lrun[qt];
        float ib[4];
#pragma unroll
        for (int r = 0; r < 4; ++r) ib[r] = __shfl(inv, g * 4 + r, 64);
#pragma unroll
        for (int r = 0; r < 4; ++r) {
            const int s = q0w + qt * 16 + g * 4 + r;
            const size_t rb = ((size_t)b * SEQ + s) * D_MODEL + h * HEAD_DIM;
#pragma unroll
            for (int dt = 0; dt < 4; ++dt) {
                const float o = oacc[qt][dt][r] * ib[r];
                const short hi = f2bf(o);
                aoh[rb + dt * 16 + a] = hi;
                aol[rb + dt * 16 + a] = f2bf(o - bf2f(hi));
            }
        }
    }
}

extern "C" void kernel_launch(void* const* d_in, const int* in_sizes, int n_in,
                              void* d_out, int out_size, void* d_ws, size_t ws_size,
                              hipStream_t stream) {
    const float* x  = (const float*)d_in[0];
    const float* wq = (const float*)d_in[1];
    const float* bq = (const float*)d_in[2];
    const float* wk = (const float*)d_in[3];
    const float* bk = (const float*)d_in[4];
    const float* wv = (const float*)d_in[5];
    const float* bv = (const float*)d_in[6];
    const float* wo = (const float*)d_in[7];
    const float* bo = (const float*)d_in[8];
    float* out = (float*)d_out;

    short* ws   = (short*)d_ws;
    short* xb   = ws;                   // 4096*1024
    short* wqT  = xb + 4194304;
    short* wkT  = wqT + 1048576;
    short* wvT  = wkT + 1048576;
    short* woTh = wvT + 1048576;
    short* woTl = woTh + 1048576;
    short* qb   = woTl + 1048576;       // 4194304 each
    short* kb   = qb + 4194304;
    short* vb   = kb + 4194304;         // holds V^T [B,H,Dh,S]
    short* aoh  = vb + 4194304;
    short* aol  = aoh + 4194304;

    xconv_kernel<<<dim3(2048), dim3(256), 0, stream>>>(x, xb);
    wconv_kernel<false><<<dim3(32, 32, 3), dim3(256), 0, stream>>>(wq, wk, wv, wqT, wkT, wvT, nullptr);
    wconv_kernel<true><<<dim3(32, 32, 1), dim3(256), 0, stream>>>(wo, nullptr, nullptr, woTh, nullptr, nullptr, woTl);

    qkv_gemm<<<dim3(8, 64, 3), dim3(256), 0, stream>>>(xb, wqT, wkT, wvT, bq, bk, bv, qb, kb, vb);

    attn2_kernel<<<dim3(512), dim3(256), 0, stream>>>(qb, kb, vb, aoh, aol);

    oproj_gemm<<<dim3(8, 64), dim3(256), 0, stream>>>(aoh, aol, woTh, woTl, bo, out);
}

// Round 5
// 155.503 us; speedup vs baseline: 10.9879x; 1.0559x over previous
//
#include <hip/hip_runtime.h>
#include <hip/hip_bf16.h>

#define D_MODEL 1024
#define NHEAD 16
#define HEAD_DIM 64
#define BATCH 2
#define SEQ 2048
#define NROWS 4096

typedef __attribute__((ext_vector_type(8))) short bf16x8;
typedef __attribute__((ext_vector_type(4))) short bf16x4;
typedef __attribute__((ext_vector_type(4))) float f32x4;

__device__ __forceinline__ short f2bf(float f) {
    __hip_bfloat16 h = __float2bfloat16(f);
    return __builtin_bit_cast(short, h);
}
__device__ __forceinline__ float bf2f(short s) {
    unsigned u = ((unsigned)(unsigned short)s) << 16;
    return __builtin_bit_cast(float, u);
}
// XOR swizzle for 128-byte LDS rows (involution; applied to source AND read)
__device__ __forceinline__ int swz128(int row, int byteoff) {
    return (row * 128 + byteoff) ^ ((row & 7) << 4);
}
// async global->LDS, 16B per lane; LDS dest = wave-uniform base + lane*16
__device__ __forceinline__ void gload16(const void* g, void* l) {
    __builtin_amdgcn_global_load_lds((const __attribute__((address_space(1))) void*)g,
                                     (__attribute__((address_space(3))) void*)l, 16, 0, 0);
}

#define QSCALE 0.18033688f  /* 0.125 * log2(e): scores land in log2 domain */

// ---------------- x fp32 -> bf16 ----------------
__global__ __launch_bounds__(256) void xconv_kernel(const float* __restrict__ x,
                                                    short* __restrict__ xb) {
    const int i = (blockIdx.x * 256 + threadIdx.x) * 8;
    float4 f0 = *(const float4*)(x + i);
    float4 f1 = *(const float4*)(x + i + 4);
    union { short s[8]; bf16x8 v; } u;
    u.s[0] = f2bf(f0.x); u.s[1] = f2bf(f0.y); u.s[2] = f2bf(f0.z); u.s[3] = f2bf(f0.w);
    u.s[4] = f2bf(f1.x); u.s[5] = f2bf(f1.y); u.s[6] = f2bf(f1.z); u.s[7] = f2bf(f1.w);
    *(bf16x8*)(xb + i) = u.v;
}

// ---------------- weight fp32 [k][n] -> bf16 transposed [n][k] (+lo) ----------------
template <bool SPLIT>
__global__ __launch_bounds__(256) void wconv_kernel(const float* __restrict__ s0,
                                                    const float* __restrict__ s1,
                                                    const float* __restrict__ s2,
                                                    short* __restrict__ d0,
                                                    short* __restrict__ d1,
                                                    short* __restrict__ d2,
                                                    short* __restrict__ dlo) {
    __shared__ float t[32][33];
    const float* src = blockIdx.z == 0 ? s0 : blockIdx.z == 1 ? s1 : s2;
    short* dst = blockIdx.z == 0 ? d0 : blockIdx.z == 1 ? d1 : d2;
    const int nb = blockIdx.x * 32, kb = blockIdx.y * 32;
    const int tx = threadIdx.x & 31, ty = threadIdx.x >> 5;
#pragma unroll
    for (int i = 0; i < 4; ++i)
        t[ty * 4 + i][tx] = src[(size_t)(kb + ty * 4 + i) * D_MODEL + nb + tx];
    __syncthreads();
#pragma unroll
    for (int i = 0; i < 4; ++i) {
        const float f = t[tx][ty * 4 + i];
        const short hi = f2bf(f);
        const size_t o = (size_t)(nb + ty * 4 + i) * D_MODEL + kb + tx;
        dst[o] = hi;
        if (SPLIT) dlo[o] = f2bf(f - bf2f(hi));
    }
}

// ---------------- fused QKV GEMM: 128x128 tile, BK=64, global_load_lds ----------------
// q,k -> [B,H,S,Dh] (q pre-scaled by 0.125*log2e); v -> transposed [B,H,Dh,S].
__global__ __launch_bounds__(256) void qkv_gemm(const short* __restrict__ xb,
                                                const short* __restrict__ wqT,
                                                const short* __restrict__ wkT,
                                                const short* __restrict__ wvT,
                                                const float* __restrict__ bq,
                                                const float* __restrict__ bk,
                                                const float* __restrict__ bv,
                                                short* __restrict__ qo,
                                                short* __restrict__ ko,
                                                short* __restrict__ vo) {
    __shared__ __align__(16) short As[128 * 64];
    __shared__ __align__(16) short Bs[128 * 64];

    const int tid = threadIdx.x;
    const int wid = tid >> 6;
    const int lane = tid & 63;
    const int a = lane & 15, g = lane >> 4;
    const int wm = wid >> 1, wn = wid & 1;

    // XCD-bijective swizzle: 768 = 8 * 96
    const int logical = (blockIdx.x & 7) * 96 + (blockIdx.x >> 3);
    const int bm = logical / 24;
    const int bnq = logical % 24;
    const int z = bnq >> 3;
    const int bn = bnq & 7;

    const short* wT = z == 0 ? wqT : z == 1 ? wkT : wvT;
    const float* bias = z == 0 ? bq : z == 1 ? bk : bv;

    // staging: per call, wave covers 8 rows x 8 segs; source seg pre-swizzled
    const int lr = lane >> 3;
    const int segl = (lane & 7) ^ lr;

    size_t asrc[4], bsrc[4];
    short *adst[4], *bdst[4];
#pragma unroll
    for (int c = 0; c < 4; ++c) {
        const int rb = c * 32 + wid * 8;
        asrc[c] = (size_t)(bm * 128 + rb + lr) * D_MODEL + segl * 8;
        bsrc[c] = (size_t)(bn * 128 + rb + lr) * D_MODEL + segl * 8;
        adst[c] = As + rb * 64;
        bdst[c] = Bs + rb * 64;
    }

    int aoff[4][2], boff[4][2];
#pragma unroll
    for (int i = 0; i < 4; ++i)
#pragma unroll
        for (int kc = 0; kc < 2; ++kc) {
            aoff[i][kc] = swz128(wm * 64 + i * 16 + a, kc * 64 + g * 16);
            boff[i][kc] = swz128(wn * 64 + i * 16 + a, kc * 64 + g * 16);
        }

    f32x4 acc[4][4];
#pragma unroll
    for (int mi = 0; mi < 4; ++mi)
#pragma unroll
        for (int ni = 0; ni < 4; ++ni) acc[mi][ni] = (f32x4){0.f, 0.f, 0.f, 0.f};

    char* const Ab = (char*)As;
    char* const Bb = (char*)Bs;

    for (int k0 = 0; k0 < D_MODEL; k0 += 64) {
        __syncthreads();
#pragma unroll
        for (int c = 0; c < 4; ++c) gload16(xb + asrc[c] + k0, adst[c]);
#pragma unroll
        for (int c = 0; c < 4; ++c) gload16(wT + bsrc[c] + k0, bdst[c]);
        __syncthreads();
        bf16x8 af[4][2], bf[4][2];
#pragma unroll
        for (int i = 0; i < 4; ++i)
#pragma unroll
            for (int kc = 0; kc < 2; ++kc) {
                af[i][kc] = *(const bf16x8*)(Ab + aoff[i][kc]);
                bf[i][kc] = *(const bf16x8*)(Bb + boff[i][kc]);
            }
#pragma unroll
        for (int kc = 0; kc < 2; ++kc)
#pragma unroll
            for (int mi = 0; mi < 4; ++mi)
#pragma unroll
                for (int ni = 0; ni < 4; ++ni)
                    acc[mi][ni] = __builtin_amdgcn_mfma_f32_16x16x32_bf16(af[mi][kc], bf[ni][kc], acc[mi][ni], 0, 0, 0);
    }

#pragma unroll
    for (int mi = 0; mi < 4; ++mi) {
        const int mbase = bm * 128 + wm * 64 + mi * 16 + g * 4;
        const int b = mbase >> 11, s = mbase & 2047;
#pragma unroll
        for (int ni = 0; ni < 4; ++ni) {
            const int col = bn * 128 + wn * 64 + ni * 16 + a;
            const int h = col >> 6, d = col & 63;
            const float bb = bias[col];
            if (z == 2) {
                union { short s4[4]; bf16x4 v; } u;
#pragma unroll
                for (int r = 0; r < 4; ++r) u.s4[r] = f2bf(acc[mi][ni][r] + bb);
                *(bf16x4*)(vo + (((size_t)(b * NHEAD + h) * HEAD_DIM + d) << 11) + s) = u.v;
            } else {
                short* dst = z == 0 ? qo : ko;
                const float sc = z == 0 ? QSCALE : 1.0f;
#pragma unroll
                for (int r = 0; r < 4; ++r)
                    dst[(((size_t)(b * NHEAD + h) * SEQ + s + r) << 6) + d] =
                        f2bf((acc[mi][ni][r] + bb) * sc);
            }
        }
    }
}

// ---------------- output projection: 3-term split, 64x128 tile, BK=64 ----------------
__global__ __launch_bounds__(256) void oproj_gemm(const short* __restrict__ aoh,
                                                  const short* __restrict__ aol,
                                                  const short* __restrict__ wTh,
                                                  const short* __restrict__ wTl,
                                                  const float* __restrict__ bo,
                                                  float* __restrict__ out) {
    __shared__ __align__(16) short Ah[64 * 64];
    __shared__ __align__(16) short Al[64 * 64];
    __shared__ __align__(16) short Bh[128 * 64];
    __shared__ __align__(16) short Bl[128 * 64];

    const int tid = threadIdx.x;
    const int wid = tid >> 6;
    const int lane = tid & 63;
    const int a = lane & 15, g = lane >> 4;
    const int wm = wid >> 1, wn = wid & 1;

    const int logical = (blockIdx.x & 7) * 64 + (blockIdx.x >> 3);  // 512 = 8*64
    const int bm = logical >> 3;   // 0..63
    const int bn = logical & 7;    // 0..7

    const int lr = lane >> 3;
    const int segl = (lane & 7) ^ lr;

    size_t asrc[2], bsrc[4];
    short *ahdst[2], *aldst[2], *bhdst[4], *bldst[4];
#pragma unroll
    for (int c = 0; c < 2; ++c) {
        const int rb = c * 32 + wid * 8;
        asrc[c] = (size_t)(bm * 64 + rb + lr) * D_MODEL + segl * 8;
        ahdst[c] = Ah + rb * 64;
        aldst[c] = Al + rb * 64;
    }
#pragma unroll
    for (int c = 0; c < 4; ++c) {
        const int rb = c * 32 + wid * 8;
        bsrc[c] = (size_t)(bn * 128 + rb + lr) * D_MODEL + segl * 8;
        bhdst[c] = Bh + rb * 64;
        bldst[c] = Bl + rb * 64;
    }

    int aoff[2][2], boff[4][2];
#pragma unroll
    for (int i = 0; i < 2; ++i)
#pragma unroll
        for (int kc = 0; kc < 2; ++kc)
            aoff[i][kc] = swz128(wm * 32 + i * 16 + a, kc * 64 + g * 16);
#pragma unroll
    for (int i = 0; i < 4; ++i)
#pragma unroll
        for (int kc = 0; kc < 2; ++kc)
            boff[i][kc] = swz128(wn * 64 + i * 16 + a, kc * 64 + g * 16);

    f32x4 acc[2][4];
#pragma unroll
    for (int mi = 0; mi < 2; ++mi)
#pragma unroll
        for (int ni = 0; ni < 4; ++ni) acc[mi][ni] = (f32x4){0.f, 0.f, 0.f, 0.f};

    char* const Ahb = (char*)Ah;
    char* const Alb = (char*)Al;
    char* const Bhb = (char*)Bh;
    char* const Blb = (char*)Bl;

    for (int k0 = 0; k0 < D_MODEL; k0 += 64) {
        __syncthreads();
#pragma unroll
        for (int c = 0; c < 2; ++c) {
            gload16(aoh + asrc[c] + k0, ahdst[c]);
            gload16(aol + asrc[c] + k0, aldst[c]);
        }
#pragma unroll
        for (int c = 0; c < 4; ++c) {
            gload16(wTh + bsrc[c] + k0, bhdst[c]);
            gload16(wTl + bsrc[c] + k0, bldst[c]);
        }
        __syncthreads();
        bf16x8 afh[2][2], afl[2][2], bfh[4][2], bfl[4][2];
#pragma unroll
        for (int i = 0; i < 2; ++i)
#pragma unroll
            for (int kc = 0; kc < 2; ++kc) {
                afh[i][kc] = *(const bf16x8*)(Ahb + aoff[i][kc]);
                afl[i][kc] = *(const bf16x8*)(Alb + aoff[i][kc]);
            }
#pragma unroll
        for (int i = 0; i < 4; ++i)
#pragma unroll
            for (int kc = 0; kc < 2; ++kc) {
                bfh[i][kc] = *(const bf16x8*)(Bhb + boff[i][kc]);
                bfl[i][kc] = *(const bf16x8*)(Blb + boff[i][kc]);
            }
#pragma unroll
        for (int kc = 0; kc < 2; ++kc)
#pragma unroll
            for (int mi = 0; mi < 2; ++mi)
#pragma unroll
                for (int ni = 0; ni < 4; ++ni) {
                    acc[mi][ni] = __builtin_amdgcn_mfma_f32_16x16x32_bf16(afh[mi][kc], bfh[ni][kc], acc[mi][ni], 0, 0, 0);
                    acc[mi][ni] = __builtin_amdgcn_mfma_f32_16x16x32_bf16(afh[mi][kc], bfl[ni][kc], acc[mi][ni], 0, 0, 0);
                    acc[mi][ni] = __builtin_amdgcn_mfma_f32_16x16x32_bf16(afl[mi][kc], bfh[ni][kc], acc[mi][ni], 0, 0, 0);
                }
    }

#pragma unroll
    for (int mi = 0; mi < 2; ++mi) {
        const int mbase = bm * 64 + wm * 32 + mi * 16 + g * 4;
#pragma unroll
        for (int ni = 0; ni < 4; ++ni) {
            const int col = bn * 128 + wn * 64 + ni * 16 + a;
            const float bb = bo[col];
#pragma unroll
            for (int r = 0; r < 4; ++r)
                out[(size_t)(mbase + r) * D_MODEL + col] = acc[mi][ni][r] + bb;
        }
    }
}

// ---------------- Flash attention v3: 8 waves, 16 q-rows/wave, exp2 domain ----------------
#define ATHR 8.0f

__global__ __launch_bounds__(512) void attn2_kernel(const short* __restrict__ q,
                                                    const short* __restrict__ k,
                                                    const short* __restrict__ vT,
                                                    short* __restrict__ aoh,
                                                    short* __restrict__ aol) {
    __shared__ __align__(16) short Ks[64 * 64];
    __shared__ __align__(16) short Vs[64 * 64];
    __shared__ __align__(16) short Ps[8][16 * 64];

    const int tid = threadIdx.x;
    const int wid = tid >> 6;
    const int lane = tid & 63;
    const int a = lane & 15;
    const int g = lane >> 4;

    const int logical = (blockIdx.x & 7) * 64 + (blockIdx.x >> 3);  // 512 = 8*64
    const int bh = logical >> 4;
    const int qc = logical & 15;
    const int q0w = qc * 128 + wid * 16;

    const size_t base = (size_t)bh * SEQ * HEAD_DIM;
    char* const Kb = (char*)Ks;
    char* const Vb = (char*)Vs;
    char* const Pb = (char*)&Ps[wid][0];

    bf16x8 qf[2];
#pragma unroll
    for (int kc = 0; kc < 2; ++kc)
        qf[kc] = *(const bf16x8*)(q + base + (size_t)(q0w + a) * HEAD_DIM + kc * 32 + g * 8);

    f32x4 oacc[4];
#pragma unroll
    for (int dt = 0; dt < 4; ++dt) oacc[dt] = (f32x4){0.f, 0.f, 0.f, 0.f};
    float mrun = -1e30f, lrun = 0.f;

    const int srow = tid >> 3;   // 0..63
    const int sseg = tid & 7;

    bf16x8 kr = *(const bf16x8*)(k + base + (size_t)srow * HEAD_DIM + sseg * 8);
    bf16x8 vr = *(const bf16x8*)(vT + base + (size_t)srow * SEQ + sseg * 8);

    for (int kt = 0; kt < SEQ / 64; ++kt) {
        __syncthreads();
        *(bf16x8*)(Kb + swz128(srow, sseg * 16)) = kr;
        *(bf16x8*)(Vb + swz128(srow, sseg * 16)) = vr;
        __syncthreads();

        if (kt + 1 < SEQ / 64) {
            kr = *(const bf16x8*)(k + base + (size_t)((kt + 1) * 64 + srow) * HEAD_DIM + sseg * 8);
            vr = *(const bf16x8*)(vT + base + (size_t)srow * SEQ + (kt + 1) * 64 + sseg * 8);
        }

        // S^T = K Q^T : lane col a = q-row, rows t4*16+g*4+r = kv
        f32x4 sacc[4];
#pragma unroll
        for (int t4 = 0; t4 < 4; ++t4) sacc[t4] = (f32x4){0.f, 0.f, 0.f, 0.f};
#pragma unroll
        for (int t4 = 0; t4 < 4; ++t4)
#pragma unroll
            for (int kc = 0; kc < 2; ++kc) {
                bf16x8 kf = *(const bf16x8*)(Kb + swz128(t4 * 16 + a, kc * 64 + g * 16));
                sacc[t4] = __builtin_amdgcn_mfma_f32_16x16x32_bf16(kf, qf[kc], sacc[t4], 0, 0, 0);
            }

        // online softmax (log2 domain; lane (a,g) owns q-row a's quarter of scores)
        {
            float tm = fmaxf(fmaxf(fmaxf(sacc[0][0], sacc[0][1]), fmaxf(sacc[0][2], sacc[0][3])),
                             fmaxf(fmaxf(sacc[1][0], sacc[1][1]), fmaxf(sacc[1][2], sacc[1][3])));
            tm = fmaxf(tm, fmaxf(fmaxf(fmaxf(sacc[2][0], sacc[2][1]), fmaxf(sacc[2][2], sacc[2][3])),
                                 fmaxf(fmaxf(sacc[3][0], sacc[3][1]), fmaxf(sacc[3][2], sacc[3][3]))));
            tm = fmaxf(tm, __shfl_xor(tm, 16, 64));
            tm = fmaxf(tm, __shfl_xor(tm, 32, 64));

            if (__any(tm > mrun + ATHR)) {
                const float mnew = fmaxf(mrun, tm);
                const float c = exp2f(mrun - mnew);
                lrun *= c;
                float cb[4];
#pragma unroll
                for (int r = 0; r < 4; ++r) cb[r] = __shfl(c, g * 4 + r, 64);
#pragma unroll
                for (int dt = 0; dt < 4; ++dt)
#pragma unroll
                    for (int r = 0; r < 4; ++r) oacc[dt][r] *= cb[r];
                mrun = mnew;
            }

            float ps = 0.f;
#pragma unroll
            for (int t4 = 0; t4 < 4; ++t4) {
                union { short s4[4]; bf16x4 v; } u;
#pragma unroll
                for (int r = 0; r < 4; ++r) {
                    const float p = exp2f(sacc[t4][r] - mrun);
                    ps += p;
                    u.s4[r] = f2bf(p);
                }
                *(bf16x4*)(Pb + swz128(a, t4 * 32 + g * 8)) = u.v;
            }
            ps += __shfl_xor(ps, 16, 64);
            ps += __shfl_xor(ps, 32, 64);
            lrun += ps;
        }

        // O += P V
        bf16x8 pf[2], vf[4][2];
#pragma unroll
        for (int kc = 0; kc < 2; ++kc)
            pf[kc] = *(const bf16x8*)(Pb + swz128(a, kc * 64 + g * 16));
#pragma unroll
        for (int dt = 0; dt < 4; ++dt)
#pragma unroll
            for (int kc = 0; kc < 2; ++kc)
                vf[dt][kc] = *(const bf16x8*)(Vb + swz128(dt * 16 + a, kc * 64 + g * 16));
#pragma unroll
        for (int dt = 0; dt < 4; ++dt)
#pragma unroll
            for (int kc = 0; kc < 2; ++kc)
                oacc[dt] = __builtin_amdgcn_mfma_f32_16x16x32_bf16(pf[kc], vf[dt][kc], oacc[dt], 0, 0, 0);
    }

    const int b = bh >> 4;
    const int h = bh & 15;
    {
        const float inv = 1.f / lrun;
        float ib[4];
#pragma unroll
        for (int r = 0; r < 4; ++r) ib[r] = __shfl(inv, g * 4 + r, 64);
#pragma unroll
        for (int r = 0; r < 4; ++r) {
            const int s = q0w + g * 4 + r;
            const size_t rb = ((size_t)b * SEQ + s) * D_MODEL + h * HEAD_DIM;
#pragma unroll
            for (int dt = 0; dt < 4; ++dt) {
                const float o = oacc[dt][r] * ib[r];
                const short hi = f2bf(o);
                aoh[rb + dt * 16 + a] = hi;
                aol[rb + dt * 16 + a] = f2bf(o - bf2f(hi));
            }
        }
    }
}

extern "C" void kernel_launch(void* const* d_in, const int* in_sizes, int n_in,
                              void* d_out, int out_size, void* d_ws, size_t ws_size,
                              hipStream_t stream) {
    const float* x  = (const float*)d_in[0];
    const float* wq = (const float*)d_in[1];
    const float* bq = (const float*)d_in[2];
    const float* wk = (const float*)d_in[3];
    const float* bk = (const float*)d_in[4];
    const float* wv = (const float*)d_in[5];
    const float* bv = (const float*)d_in[6];
    const float* wo = (const float*)d_in[7];
    const float* bo = (const float*)d_in[8];
    float* out = (float*)d_out;

    short* ws   = (short*)d_ws;
    short* xb   = ws;                   // 4096*1024
    short* wqT  = xb + 4194304;
    short* wkT  = wqT + 1048576;
    short* wvT  = wkT + 1048576;
    short* woTh = wvT + 1048576;
    short* woTl = woTh + 1048576;
    short* qb   = woTl + 1048576;       // 4194304 each
    short* kb   = qb + 4194304;
    short* vb   = kb + 4194304;         // V^T [B,H,Dh,S]
    short* aoh  = vb + 4194304;
    short* aol  = aoh + 4194304;

    xconv_kernel<<<dim3(2048), dim3(256), 0, stream>>>(x, xb);
    wconv_kernel<false><<<dim3(32, 32, 3), dim3(256), 0, stream>>>(wq, wk, wv, wqT, wkT, wvT, nullptr);
    wconv_kernel<true><<<dim3(32, 32, 1), dim3(256), 0, stream>>>(wo, nullptr, nullptr, woTh, nullptr, nullptr, woTl);

    qkv_gemm<<<dim3(768), dim3(256), 0, stream>>>(xb, wqT, wkT, wvT, bq, bk, bv, qb, kb, vb);

    attn2_kernel<<<dim3(512), dim3(512), 0, stream>>>(qb, kb, vb, aoh, aol);

    oproj_gemm<<<dim3(512), dim3(256), 0, stream>>>(aoh, aol, woTh, woTl, bo, out);
}